// Round 3
// baseline (6532.938 us; speedup 1.0000x reference)
//
#include <hip/hip_runtime.h>
#include <cstdint>
#include <cstddef>

#define N_TOK 8192
#define DIM   2048
#define VOC   32000
#define BT    256            // token rows per block
#define BV    256            // vocab cols per block
#define BKB   128            // K bytes (fp8 elems) per tile
#define NVT   (VOC / BV)     // 125 vocab tiles
#define NNT   (N_TOK / BT)   // 32 token tiles
#define KIT   (DIM / BKB)    // 16 K iterations
#define IGNORE_IDX (-100)

// prescale inputs by 2^6 at cast; both MX scales = 2^-6 (e8m0 byte 121)
// => dequant (64a * 2^-6)(64b * 2^-6) = a*b exactly.
#define PRESCALE 64.0f
#define SCALE_E8M0 0x79797979   // byte 121 replicated -> opsel-immune

typedef __attribute__((ext_vector_type(4)))  int   i32x4;
typedef __attribute__((ext_vector_type(8)))  int   i32x8;
typedef __attribute__((ext_vector_type(16))) float f32x16;

// ---------------------------------------------------------------------------
// Kernel 1: cast H and W to fp8 e4m3 (prescaled x64); zero the output.
// ---------------------------------------------------------------------------
__global__ void cast_zero_kernel(const float* __restrict__ H, const float* __restrict__ W,
                                 unsigned char* __restrict__ Hb, unsigned char* __restrict__ Wb,
                                 float* __restrict__ out)
{
    if (blockIdx.x == 0 && threadIdx.x == 0) out[0] = 0.0f;
    const size_t nh = (size_t)N_TOK * DIM / 8;
    const size_t nw = (size_t)VOC * DIM / 8;
    size_t t = (size_t)blockIdx.x * blockDim.x + threadIdx.x;
    size_t stride = (size_t)gridDim.x * blockDim.x;
    const float4* H4 = (const float4*)H;
    const float4* W4 = (const float4*)W;
    int2* Hb8 = (int2*)Hb;
    int2* Wb8 = (int2*)Wb;
    for (size_t i = t; i < nh; i += stride) {
        float4 a = H4[2 * i], b = H4[2 * i + 1];
        int lo = __builtin_amdgcn_cvt_pk_fp8_f32(a.x * PRESCALE, a.y * PRESCALE, 0, false);
        lo     = __builtin_amdgcn_cvt_pk_fp8_f32(a.z * PRESCALE, a.w * PRESCALE, lo, true);
        int hi = __builtin_amdgcn_cvt_pk_fp8_f32(b.x * PRESCALE, b.y * PRESCALE, 0, false);
        hi     = __builtin_amdgcn_cvt_pk_fp8_f32(b.z * PRESCALE, b.w * PRESCALE, hi, true);
        Hb8[i] = make_int2(lo, hi);
    }
    for (size_t i = t; i < nw; i += stride) {
        float4 a = W4[2 * i], b = W4[2 * i + 1];
        int lo = __builtin_amdgcn_cvt_pk_fp8_f32(a.x * PRESCALE, a.y * PRESCALE, 0, false);
        lo     = __builtin_amdgcn_cvt_pk_fp8_f32(a.z * PRESCALE, a.w * PRESCALE, lo, true);
        int hi = __builtin_amdgcn_cvt_pk_fp8_f32(b.x * PRESCALE, b.y * PRESCALE, 0, false);
        hi     = __builtin_amdgcn_cvt_pk_fp8_f32(b.z * PRESCALE, b.w * PRESCALE, hi, true);
        Wb8[i] = make_int2(lo, hi);
    }
}

// ---------------------------------------------------------------------------
// Kernel 2: 256x256 MX-fp8 GEMM, 8 waves (2M x 4N), dbuf LDS, 1 barrier/kt.
// r5 post-mortem: XCD remap killed HBM overfetch (2.1GB -> 0.28GB) but dur
// only -4%: LDS read pipe was the real ceiling (128^2/4-wave = 2.0 b128
// reads per MFMA; ~60% LDS-pipe busy vs 26% MfmaUtil).
// r6 (this round): 256^2 tile, wave = 128x64 -> 1.5 reads/MFMA, staged
// bytes/FLOP halved. 128KB dbuf -> 1 block/CU; latency hiding is now
// intra-block: stage(next buf) issued BEFORE compute(cur), single
// __syncthreads per kt (its vmcnt(0) drain sits after ~3600cy of compute).
// ---------------------------------------------------------------------------
#define GLOAD_LDS(gptr, lptr) __builtin_amdgcn_global_load_lds(                     \
        (const __attribute__((address_space(1))) void*)(gptr),                      \
        (__attribute__((address_space(3))) void*)(lptr), 16, 0, 0)

__device__ __forceinline__ i32x8 read_frag32(const unsigned char* lds, int rowbase, int c0, int swz)
{
    i32x4 lo = *(const i32x4*)&lds[rowbase + ((( c0     ) ^ swz) << 4)];
    i32x4 hi = *(const i32x4*)&lds[rowbase + (((c0 + 1) ^ swz) << 4)];
    return __builtin_shufflevector(lo, hi, 0, 1, 2, 3, 4, 5, 6, 7);
}

__global__ __launch_bounds__(512, 1)
void lmhead_gemm(const unsigned char* __restrict__ Hb,
                 const unsigned char* __restrict__ Wb,
                 const int* __restrict__ labels,
                 float* __restrict__ partMax,
                 float* __restrict__ partSum,
                 float* __restrict__ tgt)
{
    __shared__ unsigned char ldsA[2][BT * BKB];   // 2 x 32 KiB
    __shared__ unsigned char ldsB[2][BV * BKB];   // 2 x 32 KiB
    __shared__ float pm[4][BT];                   // 4 KiB
    __shared__ float ps[4][BT];                   // 4 KiB
    __shared__ int   ltgt[BT];                    // 1 KiB

    // XCD-aware remap (4000 = 8 XCD x 4 nt x 125 vt):
    //   xcd x owns nt band [4x, 4x+4) (A ws = 2MB, L2-resident);
    //   all XCDs sweep vt in lockstep -> each B tile LLC-served.
    int b  = blockIdx.x;
    int x  = b & 7;
    int j  = b >> 3;
    int vt = j >> 2;
    int nt = x * 4 + (j & 3);

    const int tid  = threadIdx.x;
    const int wave = tid >> 6;
    const int lane = tid & 63;
    const int wm   = wave >> 2;                // wave row (0..1) -> 128 token rows
    const int wn   = wave & 3;                 // wave col (0..3) -> 64 vocab cols
    const int l31  = lane & 31;
    const int half = lane >> 5;                // K-half within fragment

    const int rowBase = nt * BT;
    const int colBase = vt * BV;

    if (tid < BT) {
        int lb = labels[rowBase + tid];
        int lc = lb - colBase;
        ltgt[tid] = (lc >= 0 && lc < BV) ? lc : -1;
    }

    f32x16 acc[4][2];
#pragma unroll
    for (int i = 0; i < 4; ++i)
#pragma unroll
        for (int j2 = 0; j2 < 2; ++j2)
            acc[i][j2] = (f32x16){0.f,0.f,0.f,0.f,0.f,0.f,0.f,0.f,0.f,0.f,0.f,0.f,0.f,0.f,0.f,0.f};

    // staging geometry: one inst = 64 lanes x 16B = 8 rows of 128B
    const int r8   = lane >> 3;                // row within 8-row chunk
    const int c16  = lane & 7;                 // 16B slot within row
    const int gcol = ((c16 ^ r8) << 4);        // swizzled global 16B chunk

    // fragment ds_read: LDS row = tile row (stride 128B); 16B chunks XORed by row&7
    const int swz = lane & 7;                  // (tile row)&7 == lane&7 (bases %32==0)

    const unsigned char* gA = Hb + (size_t)rowBase * DIM;
    const unsigned char* gB = Wb + (size_t)colBase * DIM;

    int arow[4], brow[2];
#pragma unroll
    for (int i = 0; i < 4; ++i) arow[i] = (wm * 128 + i * 32 + l31) * BKB;
#pragma unroll
    for (int j2 = 0; j2 < 2; ++j2) brow[j2] = (wn * 64 + j2 * 32 + l31) * BKB;

    auto stage = [&](int buf, int kt) {
        const int k0 = kt * BKB;
#pragma unroll
        for (int s = 0; s < 4; ++s) {
            int chunk = s * 8 + wave;          // wave-uniform, 0..31
            int row   = chunk * 8 + r8;        // 0..255
            GLOAD_LDS(gA + (size_t)row * DIM + k0 + gcol, &ldsA[buf][chunk * 8 * BKB]);
            GLOAD_LDS(gB + (size_t)row * DIM + k0 + gcol, &ldsB[buf][chunk * 8 * BKB]);
        }
    };

    auto compute = [&](int buf) {
        const unsigned char* la = &ldsA[buf][0];
        const unsigned char* lb = &ldsB[buf][0];
#pragma unroll
        for (int kk = 0; kk < 2; ++kk) {
            const int cbase = kk * 4 + half * 2;   // 16B chunk index of this lane's 32 K-bytes
            i32x8 a0 = read_frag32(la, arow[0], cbase, swz);
            i32x8 a1 = read_frag32(la, arow[1], cbase, swz);
            i32x8 a2 = read_frag32(la, arow[2], cbase, swz);
            i32x8 a3 = read_frag32(la, arow[3], cbase, swz);
            i32x8 b0 = read_frag32(lb, brow[0], cbase, swz);
            i32x8 b1 = read_frag32(lb, brow[1], cbase, swz);
            acc[0][0] = __builtin_amdgcn_mfma_scale_f32_32x32x64_f8f6f4(
                a0, b0, acc[0][0], 0, 0, 0, SCALE_E8M0, 0, SCALE_E8M0);
            acc[0][1] = __builtin_amdgcn_mfma_scale_f32_32x32x64_f8f6f4(
                a0, b1, acc[0][1], 0, 0, 0, SCALE_E8M0, 0, SCALE_E8M0);
            acc[1][0] = __builtin_amdgcn_mfma_scale_f32_32x32x64_f8f6f4(
                a1, b0, acc[1][0], 0, 0, 0, SCALE_E8M0, 0, SCALE_E8M0);
            acc[1][1] = __builtin_amdgcn_mfma_scale_f32_32x32x64_f8f6f4(
                a1, b1, acc[1][1], 0, 0, 0, SCALE_E8M0, 0, SCALE_E8M0);
            acc[2][0] = __builtin_amdgcn_mfma_scale_f32_32x32x64_f8f6f4(
                a2, b0, acc[2][0], 0, 0, 0, SCALE_E8M0, 0, SCALE_E8M0);
            acc[2][1] = __builtin_amdgcn_mfma_scale_f32_32x32x64_f8f6f4(
                a2, b1, acc[2][1], 0, 0, 0, SCALE_E8M0, 0, SCALE_E8M0);
            acc[3][0] = __builtin_amdgcn_mfma_scale_f32_32x32x64_f8f6f4(
                a3, b0, acc[3][0], 0, 0, 0, SCALE_E8M0, 0, SCALE_E8M0);
            acc[3][1] = __builtin_amdgcn_mfma_scale_f32_32x32x64_f8f6f4(
                a3, b1, acc[3][1], 0, 0, 0, SCALE_E8M0, 0, SCALE_E8M0);
        }
    };

    // ---- dbuf main loop: prefetch kt+1 into buf^1 while computing buf ----
    stage(0, 0);
    __syncthreads();                      // tile 0 landed (vmcnt(0) drain)
    for (int kt = 0; kt < KIT; ++kt) {
        if (kt + 1 < KIT) stage((kt + 1) & 1, kt + 1);   // issue, no wait
        compute(kt & 1);                  // ~3600cy hides the load latency
        __syncthreads();                  // next tile landed; buf reusable
    }

    // ---- fused epilogue: per-row max & sum(exp) over this block's 256 cols ----
    // 32x32 C/D layout: col = lane&31, row = (reg&3) + 8*(reg>>2) + 4*(lane>>5)
#pragma unroll
    for (int i = 0; i < 4; ++i) {
#pragma unroll
        for (int r = 0; r < 16; ++r) {
            float v0 = acc[i][0][r], v1 = acc[i][1][r];
            float mx = fmaxf(v0, v1);
            mx = fmaxf(mx, __shfl_xor(mx, 1));
            mx = fmaxf(mx, __shfl_xor(mx, 2));
            mx = fmaxf(mx, __shfl_xor(mx, 4));
            mx = fmaxf(mx, __shfl_xor(mx, 8));
            mx = fmaxf(mx, __shfl_xor(mx, 16));
            float s = __expf(v0 - mx) + __expf(v1 - mx);
            s += __shfl_xor(s, 1);
            s += __shfl_xor(s, 2);
            s += __shfl_xor(s, 4);
            s += __shfl_xor(s, 8);
            s += __shfl_xor(s, 16);
            int localRow = wm * 128 + i * 32 + (r & 3) + 8 * (r >> 2) + 4 * half;
            if (l31 == 0) { pm[wn][localRow] = mx; ps[wn][localRow] = s; }
            int tc = ltgt[localRow];
            if (tc >= 0) {
#pragma unroll
                for (int jj = 0; jj < 2; ++jj) {
                    if (wn * 64 + jj * 32 + l31 == tc)
                        tgt[rowBase + localRow] = acc[i][jj][r];
                }
            }
        }
    }
    __syncthreads();

    if (tid < BT) {
        float m0 = pm[0][tid], m1 = pm[1][tid];
        float m2 = pm[2][tid], m3 = pm[3][tid];
        float M = fmaxf(fmaxf(m0, m1), fmaxf(m2, m3));
        float S = ps[0][tid] * __expf(m0 - M) + ps[1][tid] * __expf(m1 - M)
                + ps[2][tid] * __expf(m2 - M) + ps[3][tid] * __expf(m3 - M);
        size_t o = (size_t)vt * N_TOK + rowBase + tid;
        partMax[o] = M;
        partSum[o] = S;
    }
}

// ---------------------------------------------------------------------------
// Kernel 3: per-row online logsumexp over 125 tile-partials, NLL, global sum.
// ---------------------------------------------------------------------------
__global__ void reduce_kernel(const float* __restrict__ partMax,
                              const float* __restrict__ partSum,
                              const float* __restrict__ tgt,
                              const int* __restrict__ labels,
                              float* __restrict__ out)
{
    __shared__ float red[4];
    const int tid = threadIdx.x;
    const int n = blockIdx.x * blockDim.x + tid;

    float M = -1e30f, S = 0.f;
    for (int t = 0; t < NVT; ++t) {
        float m = partMax[(size_t)t * N_TOK + n];  // coalesced
        float s = partSum[(size_t)t * N_TOK + n];
        float nM = fmaxf(M, m);
        S = S * __expf(M - nM) + s * __expf(m - nM);
        M = nM;
    }
    int lb = labels[n];
    float nll = 0.f;
    if (lb != IGNORE_IDX) nll = __logf(S) + M - tgt[n];

    float v = nll;
    v += __shfl_xor(v, 32);
    v += __shfl_xor(v, 16);
    v += __shfl_xor(v, 8);
    v += __shfl_xor(v, 4);
    v += __shfl_xor(v, 2);
    v += __shfl_xor(v, 1);
    if ((tid & 63) == 0) red[tid >> 6] = v;
    __syncthreads();
    if (tid == 0) atomicAdd(out, red[0] + red[1] + red[2] + red[3]);
}

// ---------------------------------------------------------------------------
extern "C" void kernel_launch(void* const* d_in, const int* in_sizes, int n_in,
                              void* d_out, int out_size, void* d_ws, size_t ws_size,
                              hipStream_t stream)
{
    const float* H      = (const float*)d_in[0];   // [8192, 2048] fp32
    const int*   labels = (const int*)d_in[1];     // [8192]
    const float* W      = (const float*)d_in[2];   // [32000, 2048] fp32
    float* out = (float*)d_out;

    char* ws = (char*)d_ws;
    size_t need = (size_t)VOC * DIM + (size_t)N_TOK * DIM
                + 2 * (size_t)NVT * N_TOK * 4 + (size_t)N_TOK * 4;
    if (ws_size < need) return;

    unsigned char* Wb = (unsigned char*)ws;  ws += (size_t)VOC * DIM;    // 65.5 MB
    unsigned char* Hb = (unsigned char*)ws;  ws += (size_t)N_TOK * DIM;  // 16.8 MB
    float* partMax = (float*)ws;             ws += (size_t)NVT * N_TOK * 4;
    float* partSum = (float*)ws;             ws += (size_t)NVT * N_TOK * 4;
    float* tgt     = (float*)ws;

    cast_zero_kernel<<<8192, 256, 0, stream>>>(H, W, Hb, Wb, out);
    lmhead_gemm<<<NNT * NVT, 512, 0, stream>>>(Hb, Wb, labels, partMax, partSum, tgt);
    reduce_kernel<<<N_TOK / 256, 256, 0, stream>>>(partMax, partSum, tgt, labels, out);
}

// Round 4
// 1380.033 us; speedup vs baseline: 4.7339x; 4.7339x over previous
//
#include <hip/hip_runtime.h>
#include <cstdint>
#include <cstddef>

#define N_TOK 8192
#define DIM   2048
#define VOC   32000
#define BT    256            // token rows per block
#define BV    256            // vocab cols per block
#define BKB   128            // K bytes (fp8 elems) per tile
#define NVT   (VOC / BV)     // 125 vocab tiles
#define NNT   (N_TOK / BT)   // 32 token tiles
#define KIT   (DIM / BKB)    // 16 K iterations
#define IGNORE_IDX (-100)

// prescale inputs by 2^6 at cast; both MX scales = 2^-6 (e8m0 byte 121)
// => dequant (64a * 2^-6)(64b * 2^-6) = a*b exactly.
#define PRESCALE 64.0f
#define SCALE_E8M0 0x79797979   // byte 121 replicated -> opsel-immune

typedef __attribute__((ext_vector_type(4)))  int   i32x4;
typedef __attribute__((ext_vector_type(8)))  int   i32x8;
typedef __attribute__((ext_vector_type(16))) float f32x16;

// ---------------------------------------------------------------------------
// Kernel 1: cast H and W to fp8 e4m3 (prescaled x64); zero the output.
// ---------------------------------------------------------------------------
__global__ void cast_zero_kernel(const float* __restrict__ H, const float* __restrict__ W,
                                 unsigned char* __restrict__ Hb, unsigned char* __restrict__ Wb,
                                 float* __restrict__ out)
{
    if (blockIdx.x == 0 && threadIdx.x == 0) out[0] = 0.0f;
    const size_t nh = (size_t)N_TOK * DIM / 8;
    const size_t nw = (size_t)VOC * DIM / 8;
    size_t t = (size_t)blockIdx.x * blockDim.x + threadIdx.x;
    size_t stride = (size_t)gridDim.x * blockDim.x;
    const float4* H4 = (const float4*)H;
    const float4* W4 = (const float4*)W;
    int2* Hb8 = (int2*)Hb;
    int2* Wb8 = (int2*)Wb;
    for (size_t i = t; i < nh; i += stride) {
        float4 a = H4[2 * i], b = H4[2 * i + 1];
        int lo = __builtin_amdgcn_cvt_pk_fp8_f32(a.x * PRESCALE, a.y * PRESCALE, 0, false);
        lo     = __builtin_amdgcn_cvt_pk_fp8_f32(a.z * PRESCALE, a.w * PRESCALE, lo, true);
        int hi = __builtin_amdgcn_cvt_pk_fp8_f32(b.x * PRESCALE, b.y * PRESCALE, 0, false);
        hi     = __builtin_amdgcn_cvt_pk_fp8_f32(b.z * PRESCALE, b.w * PRESCALE, hi, true);
        Hb8[i] = make_int2(lo, hi);
    }
    for (size_t i = t; i < nw; i += stride) {
        float4 a = W4[2 * i], b = W4[2 * i + 1];
        int lo = __builtin_amdgcn_cvt_pk_fp8_f32(a.x * PRESCALE, a.y * PRESCALE, 0, false);
        lo     = __builtin_amdgcn_cvt_pk_fp8_f32(a.z * PRESCALE, a.w * PRESCALE, lo, true);
        int hi = __builtin_amdgcn_cvt_pk_fp8_f32(b.x * PRESCALE, b.y * PRESCALE, 0, false);
        hi     = __builtin_amdgcn_cvt_pk_fp8_f32(b.z * PRESCALE, b.w * PRESCALE, hi, true);
        Wb8[i] = make_int2(lo, hi);
    }
}

// ---------------------------------------------------------------------------
// Kernel 2: 256x256 MX-fp8 GEMM, 8 waves (2M x 4N), dbuf LDS, 1 barrier/kt.
// r6 post-mortem: acc[4][2] array + lambdas + runtime buf index -> SROA
// failed -> 512B/lane accumulator in SCRATCH (FETCH 8GB / WRITE 9.2GB,
// MfmaUtil 3.5%). Geometry was right (absmax 0, conflicts -25% as
// predicted); codegen was the failure.
// r7 (this round): spill-proof restatement of the same geometry:
//   - 8 NAMED f32x16 accumulators, zero arrays, zero lambdas
//   - 4 named __shared__ buffers; ping-pong via manual 2x unroll ->
//     every LDS base is a compile-time symbol (rule #20)
//   - launch_bounds(512,2) pins allocator at <=256 unified regs/wave
//   - ds_reads interleaved with MFMAs: peak live frags 6 -> ~3
// ---------------------------------------------------------------------------
#define GLOAD_LDS(gptr, lptr) __builtin_amdgcn_global_load_lds(                     \
        (const __attribute__((address_space(1))) void*)(gptr),                      \
        (__attribute__((address_space(3))) void*)(lptr), 16, 0, 0)

__device__ __forceinline__ i32x8 read_frag32(const unsigned char* lds, int rowbase, int c0, int swz)
{
    i32x4 lo = *(const i32x4*)&lds[rowbase + ((( c0     ) ^ swz) << 4)];
    i32x4 hi = *(const i32x4*)&lds[rowbase + (((c0 + 1) ^ swz) << 4)];
    return __builtin_shufflevector(lo, hi, 0, 1, 2, 3, 4, 5, 6, 7);
}

#define MFMA_ACC(D, A, B) D = __builtin_amdgcn_mfma_scale_f32_32x32x64_f8f6f4( \
        (A), (B), (D), 0, 0, 0, SCALE_E8M0, 0, SCALE_E8M0)

// stage one 256x128B tile pair into the named LDS buffers (8 gload_lds/wave)
#define STAGE(LA, LB, KT)                                                       \
    {                                                                           \
        const int k0_ = (KT) * BKB;                                             \
        _Pragma("unroll")                                                       \
        for (int s_ = 0; s_ < 4; ++s_) {                                        \
            int chunk_ = s_ * 8 + wave;            /* 0..31, wave-uniform */    \
            int row_   = chunk_ * 8 + r8;          /* 0..255 */                 \
            GLOAD_LDS(gA + (size_t)row_ * DIM + k0_ + gcol, &(LA)[chunk_ * 8 * BKB]); \
            GLOAD_LDS(gB + (size_t)row_ * DIM + k0_ + gcol, &(LB)[chunk_ * 8 * BKB]); \
        }                                                                       \
    }

// one K-tile of MFMAs from the named LDS buffers (16 MFMA, 24 ds_read_b128)
#define COMPUTE(LA, LB)                                                         \
    {                                                                           \
        _Pragma("unroll")                                                       \
        for (int kk_ = 0; kk_ < 2; ++kk_) {                                     \
            const int cb_ = kk_ * 4 + half * 2;                                 \
            i32x8 a0_ = read_frag32((LA), arow0, cb_, swz);                     \
            i32x8 b0_ = read_frag32((LB), brow0, cb_, swz);                     \
            MFMA_ACC(c00, a0_, b0_);                                            \
            i32x8 b1_ = read_frag32((LB), brow1, cb_, swz);                     \
            MFMA_ACC(c01, a0_, b1_);                                            \
            i32x8 a1_ = read_frag32((LA), arow1, cb_, swz);                     \
            MFMA_ACC(c10, a1_, b0_);                                            \
            MFMA_ACC(c11, a1_, b1_);                                            \
            i32x8 a2_ = read_frag32((LA), arow2, cb_, swz);                     \
            MFMA_ACC(c20, a2_, b0_);                                            \
            MFMA_ACC(c21, a2_, b1_);                                            \
            i32x8 a3_ = read_frag32((LA), arow3, cb_, swz);                     \
            MFMA_ACC(c30, a3_, b0_);                                            \
            MFMA_ACC(c31, a3_, b1_);                                            \
        }                                                                       \
    }

// epilogue for one 32-row block with its two 32-col accumulators
#define EPI(I, C0, C1)                                                          \
    _Pragma("unroll")                                                           \
    for (int r_ = 0; r_ < 16; ++r_) {                                           \
        float v0_ = (C0)[r_], v1_ = (C1)[r_];                                   \
        float mx_ = fmaxf(v0_, v1_);                                            \
        mx_ = fmaxf(mx_, __shfl_xor(mx_, 1));                                   \
        mx_ = fmaxf(mx_, __shfl_xor(mx_, 2));                                   \
        mx_ = fmaxf(mx_, __shfl_xor(mx_, 4));                                   \
        mx_ = fmaxf(mx_, __shfl_xor(mx_, 8));                                   \
        mx_ = fmaxf(mx_, __shfl_xor(mx_, 16));                                  \
        float s_ = __expf(v0_ - mx_) + __expf(v1_ - mx_);                       \
        s_ += __shfl_xor(s_, 1);                                                \
        s_ += __shfl_xor(s_, 2);                                                \
        s_ += __shfl_xor(s_, 4);                                                \
        s_ += __shfl_xor(s_, 8);                                                \
        s_ += __shfl_xor(s_, 16);                                               \
        int lr_ = wm * 128 + (I) * 32 + (r_ & 3) + 8 * (r_ >> 2) + 4 * half;    \
        if (l31 == 0) { pm[wn][lr_] = mx_; ps[wn][lr_] = s_; }                  \
        int tc_ = ltgt[lr_];                                                    \
        if (tc_ >= 0) {                                                         \
            if (wn * 64 + l31 == tc_)      tgt[rowBase + lr_] = v0_;            \
            if (wn * 64 + 32 + l31 == tc_) tgt[rowBase + lr_] = v1_;            \
        }                                                                       \
    }

__global__ __launch_bounds__(512, 2)
void lmhead_gemm(const unsigned char* __restrict__ Hb,
                 const unsigned char* __restrict__ Wb,
                 const int* __restrict__ labels,
                 float* __restrict__ partMax,
                 float* __restrict__ partSum,
                 float* __restrict__ tgt)
{
    __shared__ unsigned char ldsA0[BT * BKB];     // 32 KiB
    __shared__ unsigned char ldsA1[BT * BKB];     // 32 KiB
    __shared__ unsigned char ldsB0[BV * BKB];     // 32 KiB
    __shared__ unsigned char ldsB1[BV * BKB];     // 32 KiB
    __shared__ float pm[4][BT];                   // 4 KiB
    __shared__ float ps[4][BT];                   // 4 KiB
    __shared__ int   ltgt[BT];                    // 1 KiB

    // XCD-aware remap (4000 = 8 XCD x 4 nt x 125 vt):
    //   xcd x owns nt band [4x, 4x+4) (A ws = 2MB, L2-resident);
    //   all XCDs sweep vt in lockstep -> each B tile LLC-served.
    int b  = blockIdx.x;
    int x  = b & 7;
    int j  = b >> 3;
    int vt = j >> 2;
    int nt = x * 4 + (j & 3);

    const int tid  = threadIdx.x;
    const int wave = tid >> 6;
    const int lane = tid & 63;
    const int wm   = wave >> 2;                // wave row (0..1) -> 128 token rows
    const int wn   = wave & 3;                 // wave col (0..3) -> 64 vocab cols
    const int l31  = lane & 31;
    const int half = lane >> 5;                // K-half within fragment

    const int rowBase = nt * BT;
    const int colBase = vt * BV;

    if (tid < BT) {
        int lb = labels[rowBase + tid];
        int lc = lb - colBase;
        ltgt[tid] = (lc >= 0 && lc < BV) ? lc : -1;
    }

    // eight NAMED accumulators (128 regs total) -- no arrays, no lambdas
    f32x16 zz = (f32x16){0.f,0.f,0.f,0.f,0.f,0.f,0.f,0.f,0.f,0.f,0.f,0.f,0.f,0.f,0.f,0.f};
    f32x16 c00 = zz, c01 = zz, c10 = zz, c11 = zz;
    f32x16 c20 = zz, c21 = zz, c30 = zz, c31 = zz;

    // staging geometry: one inst = 64 lanes x 16B = 8 rows of 128B
    const int r8   = lane >> 3;                // row within 8-row chunk
    const int c16  = lane & 7;                 // 16B slot within row
    const int gcol = ((c16 ^ r8) << 4);        // swizzled global 16B chunk

    // fragment ds_read: LDS row = tile row (stride 128B); 16B chunks XORed by row&7
    const int swz = lane & 7;                  // (tile row)&7 == lane&7 (bases %32==0)

    const unsigned char* gA = Hb + (size_t)rowBase * DIM;
    const unsigned char* gB = Wb + (size_t)colBase * DIM;

    const int arow0 = (wm * 128 +  0 + l31) * BKB;
    const int arow1 = (wm * 128 + 32 + l31) * BKB;
    const int arow2 = (wm * 128 + 64 + l31) * BKB;
    const int arow3 = (wm * 128 + 96 + l31) * BKB;
    const int brow0 = (wn * 64 +  0 + l31) * BKB;
    const int brow1 = (wn * 64 + 32 + l31) * BKB;

    // ---- dbuf main loop, compile-time ping-pong (manual 2x unroll) ----
    STAGE(ldsA0, ldsB0, 0);
    __syncthreads();                       // tile 0 landed (vmcnt(0) drain)
    for (int kt2 = 0; kt2 < KIT / 2 - 1; ++kt2) {
        STAGE(ldsA1, ldsB1, 2 * kt2 + 1);  // issue, no wait
        COMPUTE(ldsA0, ldsB0);             // ~2200cy MFMA hides the latency
        __syncthreads();                   // tile 2kt2+1 landed; buf0 free
        STAGE(ldsA0, ldsB0, 2 * kt2 + 2);
        COMPUTE(ldsA1, ldsB1);
        __syncthreads();                   // tile 2kt2+2 landed; buf1 free
    }
    STAGE(ldsA1, ldsB1, KIT - 1);
    COMPUTE(ldsA0, ldsB0);                 // tile KIT-2
    __syncthreads();
    COMPUTE(ldsA1, ldsB1);                 // tile KIT-1

    // ---- fused epilogue: per-row max & sum(exp) over this block's 256 cols ----
    // 32x32 C/D layout: col = lane&31, row = (reg&3) + 8*(reg>>2) + 4*(lane>>5)
    EPI(0, c00, c01)
    EPI(1, c10, c11)
    EPI(2, c20, c21)
    EPI(3, c30, c31)
    __syncthreads();

    if (tid < BT) {
        float m0 = pm[0][tid], m1 = pm[1][tid];
        float m2 = pm[2][tid], m3 = pm[3][tid];
        float M = fmaxf(fmaxf(m0, m1), fmaxf(m2, m3));
        float S = ps[0][tid] * __expf(m0 - M) + ps[1][tid] * __expf(m1 - M)
                + ps[2][tid] * __expf(m2 - M) + ps[3][tid] * __expf(m3 - M);
        size_t o = (size_t)vt * N_TOK + rowBase + tid;
        partMax[o] = M;
        partSum[o] = S;
    }
}

// ---------------------------------------------------------------------------
// Kernel 3: per-row online logsumexp over 125 tile-partials, NLL, global sum.
// ---------------------------------------------------------------------------
__global__ void reduce_kernel(const float* __restrict__ partMax,
                              const float* __restrict__ partSum,
                              const float* __restrict__ tgt,
                              const int* __restrict__ labels,
                              float* __restrict__ out)
{
    __shared__ float red[4];
    const int tid = threadIdx.x;
    const int n = blockIdx.x * blockDim.x + tid;

    float M = -1e30f, S = 0.f;
    for (int t = 0; t < NVT; ++t) {
        float m = partMax[(size_t)t * N_TOK + n];  // coalesced
        float s = partSum[(size_t)t * N_TOK + n];
        float nM = fmaxf(M, m);
        S = S * __expf(M - nM) + s * __expf(m - nM);
        M = nM;
    }
    int lb = labels[n];
    float nll = 0.f;
    if (lb != IGNORE_IDX) nll = __logf(S) + M - tgt[n];

    float v = nll;
    v += __shfl_xor(v, 32);
    v += __shfl_xor(v, 16);
    v += __shfl_xor(v, 8);
    v += __shfl_xor(v, 4);
    v += __shfl_xor(v, 2);
    v += __shfl_xor(v, 1);
    if ((tid & 63) == 0) red[tid >> 6] = v;
    __syncthreads();
    if (tid == 0) atomicAdd(out, red[0] + red[1] + red[2] + red[3]);
}

// ---------------------------------------------------------------------------
extern "C" void kernel_launch(void* const* d_in, const int* in_sizes, int n_in,
                              void* d_out, int out_size, void* d_ws, size_t ws_size,
                              hipStream_t stream)
{
    const float* H      = (const float*)d_in[0];   // [8192, 2048] fp32
    const int*   labels = (const int*)d_in[1];     // [8192]
    const float* W      = (const float*)d_in[2];   // [32000, 2048] fp32
    float* out = (float*)d_out;

    char* ws = (char*)d_ws;
    size_t need = (size_t)VOC * DIM + (size_t)N_TOK * DIM
                + 2 * (size_t)NVT * N_TOK * 4 + (size_t)N_TOK * 4;
    if (ws_size < need) return;

    unsigned char* Wb = (unsigned char*)ws;  ws += (size_t)VOC * DIM;    // 65.5 MB
    unsigned char* Hb = (unsigned char*)ws;  ws += (size_t)N_TOK * DIM;  // 16.8 MB
    float* partMax = (float*)ws;             ws += (size_t)NVT * N_TOK * 4;
    float* partSum = (float*)ws;             ws += (size_t)NVT * N_TOK * 4;
    float* tgt     = (float*)ws;

    cast_zero_kernel<<<8192, 256, 0, stream>>>(H, W, Hb, Wb, out);
    lmhead_gemm<<<NNT * NVT, 512, 0, stream>>>(Hb, Wb, labels, partMax, partSum, tgt);
    reduce_kernel<<<N_TOK / 256, 256, 0, stream>>>(partMax, partSum, tgt, labels, out);
}